// Round 4
// baseline (742.886 us; speedup 1.0000x reference)
//
#include <hip/hip_runtime.h>
#include <hip/hip_bf16.h>

// Problem constants
#define Bc 2
#define Nc 6
#define Cc 128
#define Hc 16
#define Wc 44
#define Dc 64
#define HWc (Hc*Wc)          // 704
#define BNc (Bc*Nc)          // 12
#define NRAY (Nc*HWc)        // 4224 rays per batch
#define NPTS (Bc*Nc*Dc*HWc)  // 540672
#define BEV_W 256
#define BEV_H 256
#define BEV_HW (BEV_W*BEV_H) // 65536
#define NSEG (Bc*BEV_HW)     // 131072
#define GT 16                // cells per gather tile
#define NTILE (NSEG/GT)      // 8192

// ---------------- workspace layout (bytes) ----------------
#define OFF_KI   0                       // float Kinv[12][9]
#define OFF_DB   512                     // float dbins[64]
#define OFF_CNT  1024                    // int cnt[NSEG]      524288
#define OFF_OFFS (OFF_CNT  + 524288)     // int offs[NSEG]     524288 (block-local excl prefix)
#define OFF_FILL (OFF_OFFS + 524288)     // int fill[NSEG]     524288 (starts = offs local)
#define OFF_BSUM (OFF_FILL + 524288)     // int bsum[512]      2048   (excl-scanned block sums)
#define OFF_E8   (OFF_BSUM + 2048)       // int2 e8[NPTS]      4325376 {ray, w-bits}
#define OFF_FT   (OFF_E8   + 4325376)    // float ft[B][NRAY][128] 4325376 (channel-swizzled)
#define WS_NEED  (OFF_FT   + 4325376)    // ~9.8 MB
// fallback layout (round-2 proven path)
#define OFF_FIDX OFF_E8
#define OFF_FCNT OFF_CNT
#define WS_NEED_FB (OFF_E8 + 2162688)

// ---------------------------------------------------------------------------
// Kernel 1: numpy-f32-exact preprocessing (unchanged from round 2/3).
// ---------------------------------------------------------------------------
__global__ void k_setup(const float* __restrict__ intr, const float* __restrict__ extr,
                        const int* __restrict__ p_imgh, const int* __restrict__ p_imgw,
                        float* __restrict__ Ki, float* __restrict__ db) {
    int i = threadIdx.x;
    if (i < Dc) {
        double step = 59.0 / 63.0;
        double v = 1.0 + (double)i * step;
        db[i] = (i == Dc - 1) ? 60.0f : (float)v;   // np.linspace endpoint = stop
    }
    if (i >= BNc) return;
    double img_h = (double)p_imgh[0];
    double img_w = (double)p_imgw[0];
    double scale_x = (double)Wc / (img_w / 16.0);
    double scale_y = (double)Hc / (img_h / 16.0);
    float rs0 = (float)(16.0 / scale_x);
    float rs1 = (float)(16.0 / scale_y);
    float rs2 = 1.0f;
    const float* K = intr + i * 9;
    float k0 = __fmul_rn(K[0], rs0), k1 = __fmul_rn(K[1], rs0), k2 = __fmul_rn(K[2], rs0);
    float k3 = __fmul_rn(K[3], rs1), k4 = __fmul_rn(K[4], rs1), k5 = __fmul_rn(K[5], rs1);
    float k6 = __fmul_rn(K[6], rs2), k7 = __fmul_rn(K[7], rs2), k8 = __fmul_rn(K[8], rs2);
    float c0 = __fsub_rn(__fmul_rn(k4,k8), __fmul_rn(k5,k7));
    float c1 = __fsub_rn(__fmul_rn(k3,k8), __fmul_rn(k5,k6));
    float c2 = __fsub_rn(__fmul_rn(k3,k7), __fmul_rn(k4,k6));
    float det = __fadd_rn(__fsub_rn(__fmul_rn(k0,c0), __fmul_rn(k1,c1)), __fmul_rn(k2,c2));
    float* o = Ki + i * 9;
    o[0] = __fdiv_rn(c0, det);
    o[1] = __fdiv_rn(__fsub_rn(__fmul_rn(k2,k7), __fmul_rn(k1,k8)), det);
    o[2] = __fdiv_rn(__fsub_rn(__fmul_rn(k1,k5), __fmul_rn(k2,k4)), det);
    o[3] = __fdiv_rn(__fsub_rn(__fmul_rn(k5,k6), __fmul_rn(k3,k8)), det);
    o[4] = __fdiv_rn(__fsub_rn(__fmul_rn(k0,k8), __fmul_rn(k2,k6)), det);
    o[5] = __fdiv_rn(__fsub_rn(__fmul_rn(k2,k3), __fmul_rn(k0,k5)), det);
    o[6] = __fdiv_rn(c2, det);
    o[7] = __fdiv_rn(__fsub_rn(__fmul_rn(k1,k6), __fmul_rn(k0,k7)), det);
    o[8] = __fdiv_rn(__fsub_rn(__fmul_rn(k0,k4), __fmul_rn(k1,k3)), det);
}

// ---------------------------------------------------------------------------
// numpy-f32-exact classify: point gid -> BEV cell (or -1)
// ---------------------------------------------------------------------------
__device__ __forceinline__ int classify_point(int gid, const float* Ki_all,
                                              const float* db, const float* extr) {
    int p   = gid % HWc;
    int tmp = gid / HWc;
    int d   = tmp % Dc;
    int bn  = tmp / Dc;
    int w = p % Wc, h = p / Wc;
    float dd = db[d];
    float ud = __fmul_rn((float)w, dd);
    float vd = __fmul_rn((float)h, dd);
    const float* Ki = Ki_all + bn * 9;
    float pcx = fmaf(Ki[2], dd, fmaf(Ki[1], vd, __fmul_rn(Ki[0], ud)));
    float pcy = fmaf(Ki[5], dd, fmaf(Ki[4], vd, __fmul_rn(Ki[3], ud)));
    float pcz = fmaf(Ki[8], dd, fmaf(Ki[7], vd, __fmul_rn(Ki[6], ud)));
    const float* E = extr + bn * 16;
    float px = __fadd_rn(fmaf(E[2],  pcz, fmaf(E[1], pcy, __fmul_rn(E[0], pcx))), E[3]);
    float py = __fadd_rn(fmaf(E[6],  pcz, fmaf(E[5], pcy, __fmul_rn(E[4], pcx))), E[7]);
    float pz = __fadd_rn(fmaf(E[10], pcz, fmaf(E[9], pcy, __fmul_rn(E[8], pcx))), E[11]);
    float fx = __fdiv_rn(__fsub_rn(px, -51.2f), 0.4f);
    float fy = __fdiv_rn(__fsub_rn(py, -51.2f), 0.4f);
    int xi = (int)fx;
    int yi = (int)fy;
    bool valid = (xi >= 0) && (xi < BEV_W) && (yi >= 0) && (yi < BEV_H)
              && (pz >= -5.0f) && (pz <= 3.0f);
    return valid ? (yi * BEV_W + xi) : -1;
}

// ---------------------------------------------------------------------------
// Kernel 2: per-(b,cell) int count
// ---------------------------------------------------------------------------
__global__ __launch_bounds__(256) void k_count(const float* __restrict__ Ki_all,
                                               const float* __restrict__ db,
                                               const float* __restrict__ extr,
                                               int* __restrict__ cntArr) {
    int gid = blockIdx.x * 256 + threadIdx.x;
    if (gid >= NPTS) return;
    int cell = classify_point(gid, Ki_all, db, extr);
    if (cell >= 0) {
        int b = gid / (Nc * Dc * HWc);
        atomicAdd(&cntArr[b * BEV_HW + cell], 1);
    }
}

// ---------------------------------------------------------------------------
// Scan: block-local exclusive prefix (offs, fill) + per-block sums (bsum);
// then scan2 excl-scans the 512 block sums in place. No scan3: consumers add
// bsum[seg>>8] on the fly.
// ---------------------------------------------------------------------------
__global__ __launch_bounds__(256) void k_scan1(const int* __restrict__ cntArr,
                                               int* __restrict__ offs,
                                               int* __restrict__ fill,
                                               int* __restrict__ bsum) {
    __shared__ int s[256];
    int tid = threadIdx.x;
    int g = blockIdx.x * 256 + tid;
    int v = cntArr[g];
    s[tid] = v; __syncthreads();
    for (int st = 1; st < 256; st <<= 1) {
        int t = (tid >= st) ? s[tid - st] : 0;
        __syncthreads();
        s[tid] += t;
        __syncthreads();
    }
    int e = s[tid] - v;
    offs[g] = e;
    fill[g] = e;
    if (tid == 255) bsum[blockIdx.x] = s[255];
}

__global__ __launch_bounds__(512) void k_scan2(int* __restrict__ bsum) {
    __shared__ int s[512];
    int tid = threadIdx.x;
    int v = bsum[tid];
    s[tid] = v; __syncthreads();
    for (int st = 1; st < 512; st <<= 1) {
        int t = (tid >= st) ? s[tid - st] : 0;
        __syncthreads();
        s[tid] += t;
        __syncthreads();
    }
    bsum[tid] = s[tid] - v;   // exclusive
}

// ---------------------------------------------------------------------------
// Kernel 3: fill packed entries {ray, weight-bits} per (b,cell) segment.
// Re-classifies (VALU is free) instead of reading an idx table.
// ---------------------------------------------------------------------------
__global__ __launch_bounds__(256) void k_fill(const float* __restrict__ Ki_all,
                                              const float* __restrict__ db,
                                              const float* __restrict__ extr,
                                              const float* __restrict__ depth,
                                              int* __restrict__ fill,
                                              const int* __restrict__ bsum,
                                              int2* __restrict__ e8) {
    int gid = blockIdx.x * 256 + threadIdx.x;
    if (gid >= NPTS) return;
    int cell = classify_point(gid, Ki_all, db, extr);
    if (cell < 0) return;
    int p  = gid % HWc;
    int bn = gid / (Dc * HWc);
    int b  = bn / Nc;
    int seg = b * BEV_HW + cell;
    int pos = atomicAdd(&fill[seg], 1) + bsum[seg >> 8];
    int ray = (bn % Nc) * HWc + p;
    e8[pos] = make_int2(ray, __float_as_int(depth[gid]));
}

// ---------------------------------------------------------------------------
// Kernel 4: transpose feat [bn][c][hw] -> ft[b][ray][128] with CHANNEL SWIZZLE:
// float position 4*l+j  (l in [0,32), j in [0,4)) holds channel l + 32*j.
// So a float4 load at slot l yields channels {l, l+32, l+64, l+96} -> the
// gather's LDS atomics hit bank l for every component (conflict-free).
// ---------------------------------------------------------------------------
__global__ __launch_bounds__(256) void k_transpose(const float* __restrict__ feat,
                                                   float* __restrict__ ft) {
    __shared__ float buf[Cc * 17];
    int bn   = blockIdx.x / (HWc / 16);
    int tile = blockIdx.x % (HWc / 16);
    int tid = threadIdx.x;
    const float* fb = feat + (size_t)bn * Cc * HWc + tile * 16;
    for (int i = tid; i < Cc * 16; i += 256) {
        int c = i >> 4, hw = i & 15;
        buf[c * 17 + hw] = fb[c * HWc + hw];
    }
    __syncthreads();
    float* ob = ft + ((size_t)bn * HWc + tile * 16) * Cc;
    for (int i = tid; i < 16 * Cc; i += 256) {
        int r = i >> 7, pos = i & 127;
        int ch = (pos >> 2) + ((pos & 3) << 5);       // swizzle
        ob[(size_t)r * Cc + pos] = buf[ch * 17 + r];
    }
}

// ---------------------------------------------------------------------------
// Kernel 5: gather v2. Block = tile of 16 consecutive cells (one b).
// The tile's entries are CONTIGUOUS in e8; 8 subwarps (32 lanes) stride the
// whole range -> perfect intra-tile balance. Entry weights broadcast; ft read
// as contiguous float4 per lane; accumulate via ds_add_f32 into res[g][c]
// (bank-conflict-free thanks to the channel swizzle). 2x manual pipeline with
// e8 prefetched two iterations ahead.
// ---------------------------------------------------------------------------
__global__ __launch_bounds__(256) void k_gather(const float4* __restrict__ ft4,
                                                const int2* __restrict__ e8,
                                                const int* __restrict__ cntArr,
                                                const int* __restrict__ offs,
                                                const int* __restrict__ bsum,
                                                float* __restrict__ out) {
    __shared__ float res[GT * Cc];      // [g][c], 8 KB
    __shared__ int   sP[GT + 1];
    __shared__ int   sN[GT];
    __shared__ float sInv[GT];
    int tile  = blockIdx.x;
    int b     = tile / (BEV_HW / GT);
    int cell0 = (tile % (BEV_HW / GT)) * GT;
    int seg0  = b * BEV_HW + cell0;
    int tid   = threadIdx.x;

    for (int i = tid; i < GT * Cc; i += 256) res[i] = 0.0f;
    if (tid < GT) {
        int n = cntArr[seg0 + tid];
        sN[tid] = n;
        sInv[tid] = __fdiv_rn(1.0f, __fadd_rn((float)n, 1e-5f));
    }
    __syncthreads();
    if (tid == 0) {
        int acc = 0;
        for (int g = 0; g < GT; g++) { sP[g] = acc; acc += sN[g]; }
        sP[GT] = acc;
    }
    __syncthreads();

    int E = sP[GT];
    if (E > 0) {
        int o0 = offs[seg0] + bsum[seg0 >> 8];
        int sub = tid >> 5, l32 = tid & 31;
        const float4* ftb = ft4 + (size_t)b * NRAY * 32;
        int curG = 0;
        int kA = sub, kB = sub + 8;
        int2 eA = (kA < E) ? e8[o0 + kA] : make_int2(0, 0);
        int2 eB = (kB < E) ? e8[o0 + kB] : make_int2(0, 0);
        while (kA < E) {
            int kC = kA + 16, kD = kA + 24;
            int2 eC = (kC < E) ? e8[o0 + kC] : make_int2(0, 0);
            int2 eD = (kD < E) ? e8[o0 + kD] : make_int2(0, 0);
            while (kA >= sP[curG + 1]) curG++;
            {
                float w = __int_as_float(eA.y);
                float4 f = ftb[(size_t)eA.x * 32 + l32];
                float* r = &res[curG * Cc + l32];
                atomicAdd(r,      __fmul_rn(w, f.x));
                atomicAdd(r + 32, __fmul_rn(w, f.y));
                atomicAdd(r + 64, __fmul_rn(w, f.z));
                atomicAdd(r + 96, __fmul_rn(w, f.w));
            }
            if (kB < E) {
                while (kB >= sP[curG + 1]) curG++;
                float w = __int_as_float(eB.y);
                float4 f = ftb[(size_t)eB.x * 32 + l32];
                float* r = &res[curG * Cc + l32];
                atomicAdd(r,      __fmul_rn(w, f.x));
                atomicAdd(r + 32, __fmul_rn(w, f.y));
                atomicAdd(r + 64, __fmul_rn(w, f.z));
                atomicAdd(r + 96, __fmul_rn(w, f.w));
            }
            eA = eC; eB = eD; kA = kC; kB = kD;
        }
    }
    __syncthreads();

    // normalize + coalesced float4 stores (4 consecutive cells per store)
    float* ob = out + (size_t)b * Cc * BEV_HW + cell0;
    for (int i = tid; i < Cc * GT / 4; i += 256) {
        int c = i >> 2;
        int q = (i & 3) << 2;
        float4 v;
        v.x = __fmul_rn(res[(q + 0) * Cc + c], sInv[q + 0]);
        v.y = __fmul_rn(res[(q + 1) * Cc + c], sInv[q + 1]);
        v.z = __fmul_rn(res[(q + 2) * Cc + c], sInv[q + 2]);
        v.w = __fmul_rn(res[(q + 3) * Cc + c], sInv[q + 3]);
        *(float4*)(ob + (size_t)c * BEV_HW + q) = v;
    }
}

// ======================= fallback (round-2 proven) ==========================
__global__ __launch_bounds__(256) void k_classifyF(const float* __restrict__ Ki_all,
                                                   const float* __restrict__ db,
                                                   const float* __restrict__ extr,
                                                   int* __restrict__ idxT,
                                                   float* __restrict__ cnt) {
    int gid = blockIdx.x * 256 + threadIdx.x;
    if (gid >= NPTS) return;
    int cell = classify_point(gid, Ki_all, db, extr);
    idxT[gid] = cell;
    if (cell >= 0) {
        int b = gid / (Nc * Dc * HWc);
        atomicAdd(&cnt[b * BEV_HW + cell], 1.0f);
    }
}

__global__ __launch_bounds__(256) void k_scatterF(const float* __restrict__ feat,
                                                  const float* __restrict__ depth,
                                                  const int* __restrict__ idxT,
                                                  float* __restrict__ out) {
    __shared__ float s_dw[HWc];
    __shared__ int   s_idx[HWc];
    int blk = blockIdx.x;
    int bn  = blk / Dc;
    int b   = bn / Nc;
    int tid = threadIdx.x;
    const float* dp = depth + (size_t)blk * HWc;
    const int*   ip = idxT  + (size_t)blk * HWc;
    for (int p = tid; p < HWc; p += 256) { s_dw[p] = dp[p]; s_idx[p] = ip[p]; }
    __syncthreads();
    const float* fb = feat + (size_t)bn * Cc * HWc;
    float*       ob = out  + (size_t)b  * Cc * BEV_HW;
    for (int c = 0; c < Cc; c++) {
        const float* f = fb + (size_t)c * HWc;
        float*       o = ob + (size_t)c * BEV_HW;
        for (int p = tid; p < HWc; p += 256) {
            int cell = s_idx[p];
            if (cell >= 0) atomicAdd(&o[cell], __fmul_rn(f[p], s_dw[p]));
        }
    }
}

__global__ __launch_bounds__(256) void k_normF(float* __restrict__ out,
                                               const float* __restrict__ cnt) {
    int i = blockIdx.x * 256 + threadIdx.x;
    const int total = Bc * Cc * BEV_HW / 4;
    if (i >= total) return;
    int q = i % (BEV_HW / 4);
    int b = i / (Cc * BEV_HW / 4);
    float4 v = ((float4*)out)[i];
    float4 cv = ((const float4*)cnt)[b * (BEV_HW / 4) + q];
    v.x = __fdiv_rn(v.x, __fadd_rn(cv.x, 1e-5f));
    v.y = __fdiv_rn(v.y, __fadd_rn(cv.y, 1e-5f));
    v.z = __fdiv_rn(v.z, __fadd_rn(cv.z, 1e-5f));
    v.w = __fdiv_rn(v.w, __fadd_rn(cv.w, 1e-5f));
    ((float4*)out)[i] = v;
}

// ===========================================================================
extern "C" void kernel_launch(void* const* d_in, const int* in_sizes, int n_in,
                              void* d_out, int out_size, void* d_ws, size_t ws_size,
                              hipStream_t stream) {
    const float* feat  = (const float*)d_in[0];
    const float* depth = (const float*)d_in[1];
    const float* intr  = (const float*)d_in[2];
    const float* extr  = (const float*)d_in[3];
    const int*   imh   = (const int*)d_in[4];
    const int*   imw   = (const int*)d_in[5];
    float* out = (float*)d_out;
    char*  ws  = (char*)d_ws;
    float* Ki = (float*)(ws + OFF_KI);
    float* db = (float*)(ws + OFF_DB);

    if (ws_size >= (size_t)WS_NEED) {
        int*   cntA = (int*)(ws + OFF_CNT);
        int*   offs = (int*)(ws + OFF_OFFS);
        int*   fill = (int*)(ws + OFF_FILL);
        int*   bsum = (int*)(ws + OFF_BSUM);
        int2*  e8   = (int2*)(ws + OFF_E8);
        float* ft   = (float*)(ws + OFF_FT);

        hipMemsetAsync(cntA, 0, (size_t)NSEG * sizeof(int), stream);
        k_setup<<<1, 64, 0, stream>>>(intr, extr, imh, imw, Ki, db);
        k_count<<<(NPTS + 255) / 256, 256, 0, stream>>>(Ki, db, extr, cntA);
        k_scan1<<<NSEG / 256, 256, 0, stream>>>(cntA, offs, fill, bsum);
        k_scan2<<<1, 512, 0, stream>>>(bsum);
        k_transpose<<<BNc * (HWc / 16), 256, 0, stream>>>(feat, ft);
        k_fill<<<(NPTS + 255) / 256, 256, 0, stream>>>(Ki, db, extr, depth, fill, bsum, e8);
        k_gather<<<NTILE, 256, 0, stream>>>((const float4*)ft, e8, cntA, offs, bsum, out);
    } else {
        int*   idxT = (int*)(ws + OFF_FIDX);
        float* cnt  = (float*)(ws + OFF_FCNT);
        hipMemsetAsync(out, 0, (size_t)out_size * sizeof(float), stream);
        hipMemsetAsync(cnt, 0, (size_t)Bc * BEV_HW * sizeof(float), stream);
        k_setup<<<1, 64, 0, stream>>>(intr, extr, imh, imw, Ki, db);
        k_classifyF<<<(NPTS + 255) / 256, 256, 0, stream>>>(Ki, db, extr, idxT, cnt);
        k_scatterF<<<Bc * Nc * Dc, 256, 0, stream>>>(feat, depth, idxT, out);
        k_normF<<<(Bc * Cc * BEV_HW / 4 + 255) / 256, 256, 0, stream>>>(out, cnt);
    }
}

// Round 5
// 206.068 us; speedup vs baseline: 3.6051x; 3.6051x over previous
//
#include <hip/hip_runtime.h>
#include <hip/hip_bf16.h>

// Problem constants
#define Bc 2
#define Nc 6
#define Cc 128
#define Hc 16
#define Wc 44
#define Dc 64
#define HWc (Hc*Wc)          // 704
#define BNc (Bc*Nc)          // 12
#define NRAY (Nc*HWc)        // 4224 rays per batch
#define NPTS (Bc*Nc*Dc*HWc)  // 540672
#define BEV_W 256
#define BEV_H 256
#define BEV_HW (BEV_W*BEV_H) // 65536
#define NSEG (Bc*BEV_HW)     // 131072
#define GT 16                // cells per gather tile
#define NTILE (NSEG/GT)      // 8192

// ---------------- workspace layout (bytes) ----------------
#define OFF_KI   0                       // float Kinv[12][9]   (fallback path only)
#define OFF_DB   512                     // float dbins[64]     (fallback path only)
#define OFF_CNT  1024                    // int cnt[NSEG]      524288
#define OFF_OFFS (OFF_CNT  + 524288)     // int offs[NSEG]     524288 (block-local excl prefix)
#define OFF_FILL (OFF_OFFS + 524288)     // int fill[NSEG]     524288
#define OFF_BSUM (OFF_FILL + 524288)     // int bsum[512]      2048  (excl-scanned block sums)
#define OFF_E8   (OFF_BSUM + 2048)       // int2 e8[NPTS]      4325376 {ray, w-bits}
#define OFF_FT   (OFF_E8   + 4325376)    // float ft[B][NRAY][128] 4325376 (channel-swizzled)
#define WS_NEED  (OFF_FT   + 4325376)    // ~9.8 MB
// fallback layout (round-2 proven path)
#define OFF_FIDX OFF_E8
#define OFF_FCNT OFF_CNT

// ---------------------------------------------------------------------------
// numpy-f32-exact setup of Kinv (per bn) and dbins, into caller-provided
// arrays (LDS in the fused kernels, global in the fallback k_setup).
// ---------------------------------------------------------------------------
__device__ __forceinline__ void setup_into(int tid, const float* __restrict__ intr,
                                           const int* __restrict__ p_imgh,
                                           const int* __restrict__ p_imgw,
                                           float* Ki, float* db) {
    if (tid < Dc) {
        double v = 1.0 + (double)tid * (59.0 / 63.0);
        db[tid] = (tid == Dc - 1) ? 60.0f : (float)v;   // np.linspace endpoint = stop
    }
    if (tid >= BNc) return;
    double img_h = (double)p_imgh[0];
    double img_w = (double)p_imgw[0];
    double scale_x = (double)Wc / (img_w / 16.0);
    double scale_y = (double)Hc / (img_h / 16.0);
    float rs0 = (float)(16.0 / scale_x);
    float rs1 = (float)(16.0 / scale_y);
    float rs2 = 1.0f;
    const float* K = intr + tid * 9;
    float k0 = __fmul_rn(K[0], rs0), k1 = __fmul_rn(K[1], rs0), k2 = __fmul_rn(K[2], rs0);
    float k3 = __fmul_rn(K[3], rs1), k4 = __fmul_rn(K[4], rs1), k5 = __fmul_rn(K[5], rs1);
    float k6 = __fmul_rn(K[6], rs2), k7 = __fmul_rn(K[7], rs2), k8 = __fmul_rn(K[8], rs2);
    float c0 = __fsub_rn(__fmul_rn(k4,k8), __fmul_rn(k5,k7));
    float c1 = __fsub_rn(__fmul_rn(k3,k8), __fmul_rn(k5,k6));
    float c2 = __fsub_rn(__fmul_rn(k3,k7), __fmul_rn(k4,k6));
    float det = __fadd_rn(__fsub_rn(__fmul_rn(k0,c0), __fmul_rn(k1,c1)), __fmul_rn(k2,c2));
    float* o = Ki + tid * 9;
    o[0] = __fdiv_rn(c0, det);
    o[1] = __fdiv_rn(__fsub_rn(__fmul_rn(k2,k7), __fmul_rn(k1,k8)), det);
    o[2] = __fdiv_rn(__fsub_rn(__fmul_rn(k1,k5), __fmul_rn(k2,k4)), det);
    o[3] = __fdiv_rn(__fsub_rn(__fmul_rn(k5,k6), __fmul_rn(k3,k8)), det);
    o[4] = __fdiv_rn(__fsub_rn(__fmul_rn(k0,k8), __fmul_rn(k2,k6)), det);
    o[5] = __fdiv_rn(__fsub_rn(__fmul_rn(k2,k3), __fmul_rn(k0,k5)), det);
    o[6] = __fdiv_rn(c2, det);
    o[7] = __fdiv_rn(__fsub_rn(__fmul_rn(k1,k6), __fmul_rn(k0,k7)), det);
    o[8] = __fdiv_rn(__fsub_rn(__fmul_rn(k0,k4), __fmul_rn(k1,k3)), det);
}

// fallback-path global setup kernel
__global__ void k_setup(const float* __restrict__ intr, const float* __restrict__ extr,
                        const int* __restrict__ p_imgh, const int* __restrict__ p_imgw,
                        float* __restrict__ Ki, float* __restrict__ db) {
    setup_into(threadIdx.x, intr, p_imgh, p_imgw, Ki, db);
}

// ---------------------------------------------------------------------------
// numpy-f32-exact classify: point gid -> BEV cell (or -1)
// ---------------------------------------------------------------------------
__device__ __forceinline__ int classify_point(int gid, const float* Ki_all,
                                              const float* db, const float* extr) {
    int p   = gid % HWc;
    int tmp = gid / HWc;
    int d   = tmp % Dc;
    int bn  = tmp / Dc;
    int w = p % Wc, h = p / Wc;
    float dd = db[d];
    float ud = __fmul_rn((float)w, dd);
    float vd = __fmul_rn((float)h, dd);
    const float* Ki = Ki_all + bn * 9;
    float pcx = fmaf(Ki[2], dd, fmaf(Ki[1], vd, __fmul_rn(Ki[0], ud)));
    float pcy = fmaf(Ki[5], dd, fmaf(Ki[4], vd, __fmul_rn(Ki[3], ud)));
    float pcz = fmaf(Ki[8], dd, fmaf(Ki[7], vd, __fmul_rn(Ki[6], ud)));
    const float* E = extr + bn * 16;
    float px = __fadd_rn(fmaf(E[2],  pcz, fmaf(E[1], pcy, __fmul_rn(E[0], pcx))), E[3]);
    float py = __fadd_rn(fmaf(E[6],  pcz, fmaf(E[5], pcy, __fmul_rn(E[4], pcx))), E[7]);
    float pz = __fadd_rn(fmaf(E[10], pcz, fmaf(E[9], pcy, __fmul_rn(E[8], pcx))), E[11]);
    float fx = __fdiv_rn(__fsub_rn(px, -51.2f), 0.4f);
    float fy = __fdiv_rn(__fsub_rn(py, -51.2f), 0.4f);
    int xi = (int)fx;
    int yi = (int)fy;
    bool valid = (xi >= 0) && (xi < BEV_W) && (yi >= 0) && (yi < BEV_H)
              && (pz >= -5.0f) && (pz <= 3.0f);
    return valid ? (yi * BEV_W + xi) : -1;
}

// ---------------------------------------------------------------------------
// Kernel A: count (+ fused setup in LDS, + fused transpose in first 528 blocks)
// transpose: feat [bn][c][hw] -> ft[b][ray][128] channel-swizzled: float slot
// 4*l+j (l in [0,32), j in [0,4)) holds channel l + 32*j, so a float4 at slot l
// yields channels {l, l+32, l+64, l+96}.
// ---------------------------------------------------------------------------
__global__ __launch_bounds__(256) void k_count(const float* __restrict__ intr,
                                               const float* __restrict__ extr,
                                               const int* __restrict__ p_imgh,
                                               const int* __restrict__ p_imgw,
                                               const float* __restrict__ feat,
                                               int* __restrict__ cntArr,
                                               float* __restrict__ ft) {
    __shared__ float sKi[BNc * 9];
    __shared__ float sDb[Dc];
    __shared__ float buf[Cc * 17];
    int tid = threadIdx.x;
    setup_into(tid, intr, p_imgh, p_imgw, sKi, sDb);
    __syncthreads();
    int gid = blockIdx.x * 256 + tid;      // grid = NPTS/256 exactly
    int cell = classify_point(gid, sKi, sDb, extr);
    if (cell >= 0) {
        int b = gid / (Nc * Dc * HWc);
        atomicAdd(&cntArr[b * BEV_HW + cell], 1);
    }
    // fused transpose: blocks [0, 528) each handle one 16-ray tile
    if (blockIdx.x < BNc * (HWc / 16)) {
        int bn   = blockIdx.x / (HWc / 16);
        int tile = blockIdx.x % (HWc / 16);
        const float* fb = feat + (size_t)bn * Cc * HWc + tile * 16;
        for (int i = tid; i < Cc * 16; i += 256) {
            int c = i >> 4, hw = i & 15;
            buf[c * 17 + hw] = fb[c * HWc + hw];
        }
        __syncthreads();
        float* ob = ft + ((size_t)bn * HWc + tile * 16) * Cc;
        for (int i = tid; i < 16 * Cc; i += 256) {
            int r = i >> 7, pos = i & 127;
            int ch = (pos >> 2) + ((pos & 3) << 5);       // swizzle
            ob[(size_t)r * Cc + pos] = buf[ch * 17 + r];
        }
    }
}

// ---------------------------------------------------------------------------
// Scan: block-local exclusive prefix (offs, fill) + per-block sums; scan2
// excl-scans the 512 block sums. Consumers add bsum[seg>>8] on the fly.
// ---------------------------------------------------------------------------
__global__ __launch_bounds__(256) void k_scan1(const int* __restrict__ cntArr,
                                               int* __restrict__ offs,
                                               int* __restrict__ fill,
                                               int* __restrict__ bsum) {
    __shared__ int s[256];
    int tid = threadIdx.x;
    int g = blockIdx.x * 256 + tid;
    int v = cntArr[g];
    s[tid] = v; __syncthreads();
    for (int st = 1; st < 256; st <<= 1) {
        int t = (tid >= st) ? s[tid - st] : 0;
        __syncthreads();
        s[tid] += t;
        __syncthreads();
    }
    int e = s[tid] - v;
    offs[g] = e;
    fill[g] = e;
    if (tid == 255) bsum[blockIdx.x] = s[255];
}

__global__ __launch_bounds__(512) void k_scan2(int* __restrict__ bsum) {
    __shared__ int s[512];
    int tid = threadIdx.x;
    int v = bsum[tid];
    s[tid] = v; __syncthreads();
    for (int st = 1; st < 512; st <<= 1) {
        int t = (tid >= st) ? s[tid - st] : 0;
        __syncthreads();
        s[tid] += t;
        __syncthreads();
    }
    bsum[tid] = s[tid] - v;   // exclusive
}

// ---------------------------------------------------------------------------
// Kernel B: fill packed entries {ray, weight-bits} per (b,cell) segment.
// Re-classifies with LDS-resident Ki/db (VALU is free).
// ---------------------------------------------------------------------------
__global__ __launch_bounds__(256) void k_fill(const float* __restrict__ intr,
                                              const float* __restrict__ extr,
                                              const int* __restrict__ p_imgh,
                                              const int* __restrict__ p_imgw,
                                              const float* __restrict__ depth,
                                              int* __restrict__ fill,
                                              const int* __restrict__ bsum,
                                              int2* __restrict__ e8) {
    __shared__ float sKi[BNc * 9];
    __shared__ float sDb[Dc];
    int tid = threadIdx.x;
    setup_into(tid, intr, p_imgh, p_imgw, sKi, sDb);
    __syncthreads();
    int gid = blockIdx.x * 256 + tid;
    int cell = classify_point(gid, sKi, sDb, extr);
    if (cell < 0) return;
    int p  = gid % HWc;
    int bn = gid / (Dc * HWc);
    int b  = bn / Nc;
    int seg = b * BEV_HW + cell;
    int pos = atomicAdd(&fill[seg], 1) + bsum[seg >> 8];
    int ray = (bn % Nc) * HWc + p;
    e8[pos] = make_int2(ray, __float_as_int(depth[gid]));
}

// ---------------------------------------------------------------------------
// Kernel C: gather v3. Block = tile of 16 cells. 8 subwarps of 32 lanes;
// cells partitioned into 8 contiguous spans of ~equal ENTRY count (computed
// from the per-tile prefix). Each subwarp accumulates its cells in REGISTERS
// (float4, 2 interleaved accumulators; channel-swizzled ft), 4 entries/iter
// with next batch's e8 prefetched. NO LDS atomics (round-4 CAS-loop trap).
// ---------------------------------------------------------------------------
__global__ __launch_bounds__(256) void k_gather(const float4* __restrict__ ft4,
                                                const int2* __restrict__ e8,
                                                const int* __restrict__ cntArr,
                                                const int* __restrict__ offs,
                                                const int* __restrict__ bsum,
                                                float* __restrict__ out) {
    __shared__ float4 res4[GT * 32];     // [cell][slot] swizzled, 8 KB
    __shared__ int    sP[GT + 1];
    __shared__ float  sInv[GT];
    __shared__ int    bnd[9];
    int tile  = blockIdx.x;
    int b     = tile / (BEV_HW / GT);
    int cell0 = (tile % (BEV_HW / GT)) * GT;
    int seg0  = b * BEV_HW + cell0;
    int tid   = threadIdx.x;

    {
        float4 z4 = {0.f, 0.f, 0.f, 0.f};
        for (int i = tid; i < GT * 32; i += 256) res4[i] = z4;
    }
    if (tid < GT) {
        int n = cntArr[seg0 + tid];
        sP[tid + 1] = n;
        sInv[tid] = __fdiv_rn(1.0f, __fadd_rn((float)n, 1e-5f));
        if (tid == 0) sP[0] = 0;
    }
    __syncthreads();
    if (tid == 0) {
        for (int g = 1; g <= GT; g++) sP[g] += sP[g - 1];
    }
    __syncthreads();
    int E = sP[GT];
    if (tid < 9) {
        int t = E * tid;            // boundary s: first g with 8*sP[g] >= E*s
        int g = 0;
        while (g < GT && 8 * sP[g] < t) g++;
        bnd[tid] = g;
    }
    __syncthreads();

    if (E > 0) {
        int o0 = offs[seg0] + bsum[seg0 >> 8];
        int sub = tid >> 5, l32 = tid & 31;
        const float4* ftb = ft4 + (size_t)b * (NRAY * 32);
        const int2 z = make_int2(0, 0);
        for (int g = bnd[sub]; g < bnd[sub + 1]; g++) {
            int n = sP[g + 1] - sP[g];
            if (n <= 0) continue;
            const int2* ep = e8 + o0 + sP[g];
            float4 a0 = {0.f,0.f,0.f,0.f}, a1 = {0.f,0.f,0.f,0.f};
            int2 c0 = ep[0];
            int2 c1 = (1 < n) ? ep[1] : z;
            int2 c2 = (2 < n) ? ep[2] : z;
            int2 c3 = (3 < n) ? ep[3] : z;
            for (int e = 0; e < n; e += 4) {
                int eb = e + 4;
                int2 n0 = (eb + 0 < n) ? ep[eb + 0] : z;
                int2 n1 = (eb + 1 < n) ? ep[eb + 1] : z;
                int2 n2 = (eb + 2 < n) ? ep[eb + 2] : z;
                int2 n3 = (eb + 3 < n) ? ep[eb + 3] : z;
                float4 f0 = ftb[(size_t)c0.x * 32 + l32];
                float4 f1 = ftb[(size_t)c1.x * 32 + l32];
                float4 f2 = ftb[(size_t)c2.x * 32 + l32];
                float4 f3 = ftb[(size_t)c3.x * 32 + l32];
                float w0 = __int_as_float(c0.y), w1 = __int_as_float(c1.y);
                float w2 = __int_as_float(c2.y), w3 = __int_as_float(c3.y);
                a0.x = fmaf(w0, f0.x, a0.x); a0.y = fmaf(w0, f0.y, a0.y);
                a0.z = fmaf(w0, f0.z, a0.z); a0.w = fmaf(w0, f0.w, a0.w);
                a1.x = fmaf(w1, f1.x, a1.x); a1.y = fmaf(w1, f1.y, a1.y);
                a1.z = fmaf(w1, f1.z, a1.z); a1.w = fmaf(w1, f1.w, a1.w);
                a0.x = fmaf(w2, f2.x, a0.x); a0.y = fmaf(w2, f2.y, a0.y);
                a0.z = fmaf(w2, f2.z, a0.z); a0.w = fmaf(w2, f2.w, a0.w);
                a1.x = fmaf(w3, f3.x, a1.x); a1.y = fmaf(w3, f3.y, a1.y);
                a1.z = fmaf(w3, f3.z, a1.z); a1.w = fmaf(w3, f3.w, a1.w);
                c0 = n0; c1 = n1; c2 = n2; c3 = n3;
            }
            float4 s;
            s.x = __fadd_rn(a0.x, a1.x);
            s.y = __fadd_rn(a0.y, a1.y);
            s.z = __fadd_rn(a0.z, a1.z);
            s.w = __fadd_rn(a0.w, a1.w);
            res4[g * 32 + l32] = s;
        }
    }
    __syncthreads();

    // normalize + store: 4-lane clusters cover 16 consecutive cells of one
    // channel -> full 64B lines.
    const float* resf = (const float*)res4;
    float* ob = out + (size_t)b * Cc * BEV_HW + cell0;
    for (int i = tid; i < Cc * GT / 4; i += 256) {    // 512 float4 stores
        int quad = i & 3;
        int c    = i >> 2;
        int pos  = ((c & 31) << 2) | (c >> 5);        // slot of channel c
        int g0 = quad * 4;
        float4 v;
        v.x = __fmul_rn(resf[(g0 + 0) * Cc + pos], sInv[g0 + 0]);
        v.y = __fmul_rn(resf[(g0 + 1) * Cc + pos], sInv[g0 + 1]);
        v.z = __fmul_rn(resf[(g0 + 2) * Cc + pos], sInv[g0 + 2]);
        v.w = __fmul_rn(resf[(g0 + 3) * Cc + pos], sInv[g0 + 3]);
        *(float4*)(ob + (size_t)c * BEV_HW + g0) = v;
    }
}

// ======================= fallback (round-2 proven) ==========================
__global__ __launch_bounds__(256) void k_classifyF(const float* __restrict__ Ki_all,
                                                   const float* __restrict__ db,
                                                   const float* __restrict__ extr,
                                                   int* __restrict__ idxT,
                                                   float* __restrict__ cnt) {
    int gid = blockIdx.x * 256 + threadIdx.x;
    if (gid >= NPTS) return;
    int cell = classify_point(gid, Ki_all, db, extr);
    idxT[gid] = cell;
    if (cell >= 0) {
        int b = gid / (Nc * Dc * HWc);
        atomicAdd(&cnt[b * BEV_HW + cell], 1.0f);
    }
}

__global__ __launch_bounds__(256) void k_scatterF(const float* __restrict__ feat,
                                                  const float* __restrict__ depth,
                                                  const int* __restrict__ idxT,
                                                  float* __restrict__ out) {
    __shared__ float s_dw[HWc];
    __shared__ int   s_idx[HWc];
    int blk = blockIdx.x;
    int bn  = blk / Dc;
    int b   = bn / Nc;
    int tid = threadIdx.x;
    const float* dp = depth + (size_t)blk * HWc;
    const int*   ip = idxT  + (size_t)blk * HWc;
    for (int p = tid; p < HWc; p += 256) { s_dw[p] = dp[p]; s_idx[p] = ip[p]; }
    __syncthreads();
    const float* fb = feat + (size_t)bn * Cc * HWc;
    float*       ob = out  + (size_t)b  * Cc * BEV_HW;
    for (int c = 0; c < Cc; c++) {
        const float* f = fb + (size_t)c * HWc;
        float*       o = ob + (size_t)c * BEV_HW;
        for (int p = tid; p < HWc; p += 256) {
            int cell = s_idx[p];
            if (cell >= 0) atomicAdd(&o[cell], __fmul_rn(f[p], s_dw[p]));
        }
    }
}

__global__ __launch_bounds__(256) void k_normF(float* __restrict__ out,
                                               const float* __restrict__ cnt) {
    int i = blockIdx.x * 256 + threadIdx.x;
    const int total = Bc * Cc * BEV_HW / 4;
    if (i >= total) return;
    int q = i % (BEV_HW / 4);
    int b = i / (Cc * BEV_HW / 4);
    float4 v = ((float4*)out)[i];
    float4 cv = ((const float4*)cnt)[b * (BEV_HW / 4) + q];
    v.x = __fdiv_rn(v.x, __fadd_rn(cv.x, 1e-5f));
    v.y = __fdiv_rn(v.y, __fadd_rn(cv.y, 1e-5f));
    v.z = __fdiv_rn(v.z, __fadd_rn(cv.z, 1e-5f));
    v.w = __fdiv_rn(v.w, __fadd_rn(cv.w, 1e-5f));
    ((float4*)out)[i] = v;
}

// ===========================================================================
extern "C" void kernel_launch(void* const* d_in, const int* in_sizes, int n_in,
                              void* d_out, int out_size, void* d_ws, size_t ws_size,
                              hipStream_t stream) {
    const float* feat  = (const float*)d_in[0];
    const float* depth = (const float*)d_in[1];
    const float* intr  = (const float*)d_in[2];
    const float* extr  = (const float*)d_in[3];
    const int*   imh   = (const int*)d_in[4];
    const int*   imw   = (const int*)d_in[5];
    float* out = (float*)d_out;
    char*  ws  = (char*)d_ws;

    if (ws_size >= (size_t)WS_NEED) {
        int*   cntA = (int*)(ws + OFF_CNT);
        int*   offs = (int*)(ws + OFF_OFFS);
        int*   fill = (int*)(ws + OFF_FILL);
        int*   bsum = (int*)(ws + OFF_BSUM);
        int2*  e8   = (int2*)(ws + OFF_E8);
        float* ft   = (float*)(ws + OFF_FT);

        hipMemsetAsync(cntA, 0, (size_t)NSEG * sizeof(int), stream);
        k_count<<<NPTS / 256, 256, 0, stream>>>(intr, extr, imh, imw, feat, cntA, ft);
        k_scan1<<<NSEG / 256, 256, 0, stream>>>(cntA, offs, fill, bsum);
        k_scan2<<<1, 512, 0, stream>>>(bsum);
        k_fill<<<NPTS / 256, 256, 0, stream>>>(intr, extr, imh, imw, depth, fill, bsum, e8);
        k_gather<<<NTILE, 256, 0, stream>>>((const float4*)ft, e8, cntA, offs, bsum, out);
    } else {
        float* Ki   = (float*)(ws + OFF_KI);
        float* db   = (float*)(ws + OFF_DB);
        int*   idxT = (int*)(ws + OFF_FIDX);
        float* cnt  = (float*)(ws + OFF_FCNT);
        hipMemsetAsync(out, 0, (size_t)out_size * sizeof(float), stream);
        hipMemsetAsync(cnt, 0, (size_t)Bc * BEV_HW * sizeof(float), stream);
        k_setup<<<1, 64, 0, stream>>>(intr, extr, imh, imw, Ki, db);
        k_classifyF<<<(NPTS + 255) / 256, 256, 0, stream>>>(Ki, db, extr, idxT, cnt);
        k_scatterF<<<Bc * Nc * Dc, 256, 0, stream>>>(feat, depth, idxT, out);
        k_normF<<<(Bc * Cc * BEV_HW / 4 + 255) / 256, 256, 0, stream>>>(out, cnt);
    }
}

// Round 7
// 188.485 us; speedup vs baseline: 3.9413x; 1.0933x over previous
//
#include <hip/hip_runtime.h>
#include <hip/hip_bf16.h>

// Problem constants
#define Bc 2
#define Nc 6
#define Cc 128
#define Hc 16
#define Wc 44
#define Dc 64
#define HWc (Hc*Wc)          // 704
#define BNc (Bc*Nc)          // 12
#define NRAY (Nc*HWc)        // 4224 rays per batch
#define NPTS (Bc*Nc*Dc*HWc)  // 540672
#define BEV_W 256
#define BEV_H 256
#define BEV_HW (BEV_W*BEV_H) // 65536
#define NSEG (Bc*BEV_HW)     // 131072
#define GT 16                // cells per gather tile
#define NTILE (NSEG/GT)      // 8192 total (4096 per batch)

// ---------------- workspace layout (bytes) ----------------
#define OFF_KI   0                       // float Kinv[12][9]   (fallback path only)
#define OFF_DB   512                     // float dbins[64]     (fallback path only)
#define OFF_CNT  1024                    // int cnt[NSEG]      524288
#define OFF_OFFS (OFF_CNT  + 524288)     // int offs[NSEG]     524288 (scan1-block-local excl prefix)
#define OFF_FILL (OFF_OFFS + 524288)     // int fill[NSEG]     524288
#define OFF_BSUM (OFF_FILL + 524288)     // int bsum[256]      2048  (excl-scanned block sums)
#define OFF_E8   (OFF_BSUM + 2048)       // int2 e8[NPTS]      4325376 {ray|cell<<16, w-bits}
#define OFF_FT   (OFF_E8   + 4325376)    // float ft[B][NRAY][128] 4325376 (plain layout)
#define WS_NEED  (OFF_FT   + 4325376)    // ~9.8 MB
// fallback layout (round-2 proven path)
#define OFF_FIDX OFF_E8
#define OFF_FCNT OFF_CNT

// ---------------------------------------------------------------------------
// numpy-f32-exact setup of Kinv (per bn) and dbins.
// ---------------------------------------------------------------------------
__device__ __forceinline__ void setup_into(int tid, const float* __restrict__ intr,
                                           const int* __restrict__ p_imgh,
                                           const int* __restrict__ p_imgw,
                                           float* Ki, float* db) {
    if (tid < Dc) {
        double v = 1.0 + (double)tid * (59.0 / 63.0);
        db[tid] = (tid == Dc - 1) ? 60.0f : (float)v;   // np.linspace endpoint = stop
    }
    if (tid >= BNc) return;
    double img_h = (double)p_imgh[0];
    double img_w = (double)p_imgw[0];
    double scale_x = (double)Wc / (img_w / 16.0);
    double scale_y = (double)Hc / (img_h / 16.0);
    float rs0 = (float)(16.0 / scale_x);
    float rs1 = (float)(16.0 / scale_y);
    float rs2 = 1.0f;
    const float* K = intr + tid * 9;
    float k0 = __fmul_rn(K[0], rs0), k1 = __fmul_rn(K[1], rs0), k2 = __fmul_rn(K[2], rs0);
    float k3 = __fmul_rn(K[3], rs1), k4 = __fmul_rn(K[4], rs1), k5 = __fmul_rn(K[5], rs1);
    float k6 = __fmul_rn(K[6], rs2), k7 = __fmul_rn(K[7], rs2), k8 = __fmul_rn(K[8], rs2);
    float c0 = __fsub_rn(__fmul_rn(k4,k8), __fmul_rn(k5,k7));
    float c1 = __fsub_rn(__fmul_rn(k3,k8), __fmul_rn(k5,k6));
    float c2 = __fsub_rn(__fmul_rn(k3,k7), __fmul_rn(k4,k6));
    float det = __fadd_rn(__fsub_rn(__fmul_rn(k0,c0), __fmul_rn(k1,c1)), __fmul_rn(k2,c2));
    float* o = Ki + tid * 9;
    o[0] = __fdiv_rn(c0, det);
    o[1] = __fdiv_rn(__fsub_rn(__fmul_rn(k2,k7), __fmul_rn(k1,k8)), det);
    o[2] = __fdiv_rn(__fsub_rn(__fmul_rn(k1,k5), __fmul_rn(k2,k4)), det);
    o[3] = __fdiv_rn(__fsub_rn(__fmul_rn(k5,k6), __fmul_rn(k3,k8)), det);
    o[4] = __fdiv_rn(__fsub_rn(__fmul_rn(k0,k8), __fmul_rn(k2,k6)), det);
    o[5] = __fdiv_rn(__fsub_rn(__fmul_rn(k2,k3), __fmul_rn(k0,k5)), det);
    o[6] = __fdiv_rn(c2, det);
    o[7] = __fdiv_rn(__fsub_rn(__fmul_rn(k1,k6), __fmul_rn(k0,k7)), det);
    o[8] = __fdiv_rn(__fsub_rn(__fmul_rn(k0,k4), __fmul_rn(k1,k3)), det);
}

// fallback-path global setup kernel
__global__ void k_setup(const float* __restrict__ intr, const float* __restrict__ extr,
                        const int* __restrict__ p_imgh, const int* __restrict__ p_imgw,
                        float* __restrict__ Ki, float* __restrict__ db) {
    setup_into(threadIdx.x, intr, p_imgh, p_imgw, Ki, db);
}

// ---------------------------------------------------------------------------
// numpy-f32-exact classify: point gid -> BEV cell (or -1)
// ---------------------------------------------------------------------------
__device__ __forceinline__ int classify_point(int gid, const float* Ki_all,
                                              const float* db, const float* extr) {
    int p   = gid % HWc;
    int tmp = gid / HWc;
    int d   = tmp % Dc;
    int bn  = tmp / Dc;
    int w = p % Wc, h = p / Wc;
    float dd = db[d];
    float ud = __fmul_rn((float)w, dd);
    float vd = __fmul_rn((float)h, dd);
    const float* Ki = Ki_all + bn * 9;
    float pcx = fmaf(Ki[2], dd, fmaf(Ki[1], vd, __fmul_rn(Ki[0], ud)));
    float pcy = fmaf(Ki[5], dd, fmaf(Ki[4], vd, __fmul_rn(Ki[3], ud)));
    float pcz = fmaf(Ki[8], dd, fmaf(Ki[7], vd, __fmul_rn(Ki[6], ud)));
    const float* E = extr + bn * 16;
    float px = __fadd_rn(fmaf(E[2],  pcz, fmaf(E[1], pcy, __fmul_rn(E[0], pcx))), E[3]);
    float py = __fadd_rn(fmaf(E[6],  pcz, fmaf(E[5], pcy, __fmul_rn(E[4], pcx))), E[7]);
    float pz = __fadd_rn(fmaf(E[10], pcz, fmaf(E[9], pcy, __fmul_rn(E[8], pcx))), E[11]);
    float fx = __fdiv_rn(__fsub_rn(px, -51.2f), 0.4f);
    float fy = __fdiv_rn(__fsub_rn(py, -51.2f), 0.4f);
    int xi = (int)fx;
    int yi = (int)fy;
    bool valid = (xi >= 0) && (xi < BEV_W) && (yi >= 0) && (yi < BEV_H)
              && (pz >= -5.0f) && (pz <= 3.0f);
    return valid ? (yi * BEV_W + xi) : -1;
}

// ---------------------------------------------------------------------------
// Kernel A: count (+ fused setup in LDS, + fused transpose in first 528 blocks)
// transpose: feat [bn][c][hw] -> ft[b][ray][c] (plain channel order)
// ---------------------------------------------------------------------------
__global__ __launch_bounds__(256) void k_count(const float* __restrict__ intr,
                                               const float* __restrict__ extr,
                                               const int* __restrict__ p_imgh,
                                               const int* __restrict__ p_imgw,
                                               const float* __restrict__ feat,
                                               int* __restrict__ cntArr,
                                               float* __restrict__ ft) {
    __shared__ float sKi[BNc * 9];
    __shared__ float sDb[Dc];
    __shared__ float buf[Cc * 17];
    int tid = threadIdx.x;
    setup_into(tid, intr, p_imgh, p_imgw, sKi, sDb);
    __syncthreads();
    int gid = blockIdx.x * 256 + tid;      // grid = NPTS/256 exactly
    int cell = classify_point(gid, sKi, sDb, extr);
    if (cell >= 0) {
        int b = gid / (Nc * Dc * HWc);
        atomicAdd(&cntArr[b * BEV_HW + cell], 1);
    }
    // fused transpose: blocks [0, 528) each handle one 16-ray tile
    if (blockIdx.x < BNc * (HWc / 16)) {
        int bn   = blockIdx.x / (HWc / 16);
        int tile = blockIdx.x % (HWc / 16);
        const float* fb = feat + (size_t)bn * Cc * HWc + tile * 16;
        for (int i = tid; i < Cc * 16; i += 256) {
            int c = i >> 4, hw = i & 15;
            buf[c * 17 + hw] = fb[c * HWc + hw];
        }
        __syncthreads();
        float* obt = ft + ((size_t)bn * HWc + tile * 16) * Cc;
        for (int i = tid; i < 16 * Cc; i += 256) {
            int r = i >> 7, ch = i & 127;
            obt[(size_t)r * Cc + ch] = buf[ch * 17 + r];
        }
    }
}

// ---------------------------------------------------------------------------
// Scan: 512-thread block-local exclusive prefix (offs, fill) + 256 block
// sums; scan2 excl-scans them. Consumers add bsum[seg>>9] on the fly.
// ---------------------------------------------------------------------------
__global__ __launch_bounds__(512) void k_scan1(const int* __restrict__ cntArr,
                                               int* __restrict__ offs,
                                               int* __restrict__ fill,
                                               int* __restrict__ bsum) {
    __shared__ int s[512];
    int tid = threadIdx.x;
    int g = blockIdx.x * 512 + tid;
    int v = cntArr[g];
    s[tid] = v; __syncthreads();
    for (int st = 1; st < 512; st <<= 1) {
        int t = (tid >= st) ? s[tid - st] : 0;
        __syncthreads();
        s[tid] += t;
        __syncthreads();
    }
    int e = s[tid] - v;
    offs[g] = e;
    fill[g] = e;
    if (tid == 511) bsum[blockIdx.x] = s[511];
}

__global__ __launch_bounds__(256) void k_scan2(int* __restrict__ bsum) {
    __shared__ int s[256];
    int tid = threadIdx.x;
    int v = bsum[tid];
    s[tid] = v; __syncthreads();
    for (int st = 1; st < 256; st <<= 1) {
        int t = (tid >= st) ? s[tid - st] : 0;
        __syncthreads();
        s[tid] += t;
        __syncthreads();
    }
    bsum[tid] = s[tid] - v;   // exclusive
}

// ---------------------------------------------------------------------------
// Kernel B: fill packed entries {ray | cellLocal<<16, weight-bits}.
// ---------------------------------------------------------------------------
__global__ __launch_bounds__(256) void k_fill(const float* __restrict__ intr,
                                              const float* __restrict__ extr,
                                              const int* __restrict__ p_imgh,
                                              const int* __restrict__ p_imgw,
                                              const float* __restrict__ depth,
                                              int* __restrict__ fill,
                                              const int* __restrict__ bsum,
                                              int2* __restrict__ e8) {
    __shared__ float sKi[BNc * 9];
    __shared__ float sDb[Dc];
    int tid = threadIdx.x;
    setup_into(tid, intr, p_imgh, p_imgw, sKi, sDb);
    __syncthreads();
    int gid = blockIdx.x * 256 + tid;
    int cell = classify_point(gid, sKi, sDb, extr);
    if (cell < 0) return;
    int p  = gid % HWc;
    int bn = gid / (Dc * HWc);
    int b  = bn / Nc;
    int seg = b * BEV_HW + cell;
    int pos = atomicAdd(&fill[seg], 1) + bsum[seg >> 9];
    int ray = (bn % Nc) * HWc + p;
    e8[pos] = make_int2(ray | ((cell & (GT - 1)) << 16), __float_as_int(depth[gid]));
}

// ---------------------------------------------------------------------------
// Kernel C: gather v4 (fixed tile decode). Block = 16-cell tile (center-first
// swizzle). 4 waves stride the tile's entry list (stride 4). One FULL WAVE
// per entry: lane l holds channels {2l, 2l+1} (float2) -> cell is
// wave-uniform, no divergence. Entries are cell-sorted, so each wave's walk
// is cell-monotonic: accumulate in registers, flush on cell-change as a PURE
// ds_write into the wave's private LDS region (no atomics, no RMW).
// Groups of 8 entries with e8 prefetched one group ahead -> 8 independent
// ft loads in flight. Epilogue sums the 4 regions, normalizes, stores.
// ---------------------------------------------------------------------------
#define RSTRIDE 132              // floats per cell slot (132 ≡ 4 mod 32: no epi bank conflicts)
#define RSZ (GT * RSTRIDE)       // 2112 floats per wave region
__global__ __launch_bounds__(256) void k_gather(const float2* __restrict__ ft2,
                                                const int2* __restrict__ e8,
                                                const int* __restrict__ cntArr,
                                                const int* __restrict__ offs,
                                                const int* __restrict__ bsum,
                                                float* __restrict__ out) {
    __shared__ float4 accv[RSZ];         // 4 regions * 2112 floats = 33792 B
    __shared__ float  sInv[GT];
    __shared__ int    sCnt[GT];
    __shared__ int    sO[2];
    float* accf = (float*)accv;

    int idx = blockIdx.x;
    int b   = idx >> 12;                 // 4096 tiles per batch  (BUGFIX: was >>13)
    int t   = idx & 4095;                //                        (BUGFIX: was &8191)
    int ri  = t >> 4, ci = t & 15;       // ri in [0,256), ci in [0,16)
    int row = (ri & 1) ? (127 - (ri >> 1)) : (128 + (ri >> 1));   // center-first rows, bijective on [0,256)
    int col = (ci & 1) ? (7  - (ci >> 1)) : (8  + (ci >> 1));     // center-first cols, bijective on [0,16)
    int cell0 = row * BEV_W + col * GT;
    int seg0  = b * BEV_HW + cell0;
    int tid = threadIdx.x;

    for (int i = tid; i < RSZ; i += 256) accv[i] = make_float4(0.f, 0.f, 0.f, 0.f);
    if (tid < GT) {
        int n = cntArr[seg0 + tid];
        sCnt[tid] = n;
        sInv[tid] = __fdiv_rn(1.0f, __fadd_rn((float)n, 1e-5f));
    }
    __syncthreads();
    if (tid == 0) {
        int s = 0;
        for (int g = 0; g < GT; g++) s += sCnt[g];
        sO[0] = offs[seg0] + bsum[seg0 >> 9];
        sO[1] = s;
    }
    __syncthreads();
    int o0 = sO[0], E = sO[1];

    int w = tid >> 6, lane = tid & 63;
    float* accw = accf + w * RSZ;
    if (E > w) {
        const float2* ftb = ft2 + (size_t)b * (NRAY * 64);
        int nt = (E - w + 3) >> 2;       // entries for this wave (k = w + 4*t)
        const int U = 8;
        int ngr = nt / U;
        float2 a = make_float2(0.f, 0.f);
        int curc = -1;
        if (ngr > 0) {
            int2 e[U];
            #pragma unroll
            for (int u = 0; u < U; u++) e[u] = e8[o0 + w + 4 * u];
            for (int g = 0; g < ngr; g++) {
                float2 f[U];
                #pragma unroll
                for (int u = 0; u < U; u++)
                    f[u] = ftb[(size_t)(e[u].x & 0xFFFF) * 64 + lane];
                int2 en[U];
                if (g + 1 < ngr) {
                    #pragma unroll
                    for (int u = 0; u < U; u++)
                        en[u] = e8[o0 + w + 4 * ((g + 1) * U + u)];
                } else {
                    #pragma unroll
                    for (int u = 0; u < U; u++) en[u] = e[u];
                }
                #pragma unroll
                for (int u = 0; u < U; u++) {
                    int c = e[u].x >> 16;                  // wave-uniform
                    if (c != curc) {
                        if (curc >= 0) *(float2*)(accw + curc * RSTRIDE + 2 * lane) = a;
                        curc = c; a.x = 0.f; a.y = 0.f;
                    }
                    float ww = __int_as_float(e[u].y);
                    a.x = fmaf(ww, f[u].x, a.x);
                    a.y = fmaf(ww, f[u].y, a.y);
                }
                #pragma unroll
                for (int u = 0; u < U; u++) e[u] = en[u];
            }
        }
        // batched tail (no serial dependent chain)
        int rem = nt - ngr * U;
        if (rem > 0) {
            int2 et[U];
            #pragma unroll
            for (int u = 0; u < U; u++)
                if (u < rem) et[u] = e8[o0 + w + 4 * (ngr * U + u)];
            float2 ftl[U];
            #pragma unroll
            for (int u = 0; u < U; u++)
                if (u < rem) ftl[u] = ftb[(size_t)(et[u].x & 0xFFFF) * 64 + lane];
            #pragma unroll
            for (int u = 0; u < U; u++)
                if (u < rem) {
                    int c = et[u].x >> 16;
                    if (c != curc) {
                        if (curc >= 0) *(float2*)(accw + curc * RSTRIDE + 2 * lane) = a;
                        curc = c; a.x = 0.f; a.y = 0.f;
                    }
                    float ww = __int_as_float(et[u].y);
                    a.x = fmaf(ww, ftl[u].x, a.x);
                    a.y = fmaf(ww, ftl[u].y, a.y);
                }
        }
        if (curc >= 0) *(float2*)(accw + curc * RSTRIDE + 2 * lane) = a;
    }
    __syncthreads();

    // epilogue: sum 4 regions, normalize, coalesced float4 stores
    // lanes 0..3 cover cells 0..15 of one channel = full 64 B line
    float* ob = out + (size_t)b * Cc * BEV_HW + cell0;
    for (int i = tid; i < Cc * GT / 4; i += 256) {   // 512 float4 stores
        int q = i & 3, c = i >> 2;
        float4 v;
        #pragma unroll
        for (int k = 0; k < 4; k++) {
            int g = q * 4 + k;
            int base = g * RSTRIDE + c;
            float s = __fadd_rn(__fadd_rn(accf[base], accf[RSZ + base]),
                                __fadd_rn(accf[2 * RSZ + base], accf[3 * RSZ + base]));
            (&v.x)[k] = __fmul_rn(s, sInv[g]);
        }
        *(float4*)(ob + (size_t)c * BEV_HW + q * 4) = v;
    }
}

// ======================= fallback (round-2 proven) ==========================
__global__ __launch_bounds__(256) void k_classifyF(const float* __restrict__ Ki_all,
                                                   const float* __restrict__ db,
                                                   const float* __restrict__ extr,
                                                   int* __restrict__ idxT,
                                                   float* __restrict__ cnt) {
    int gid = blockIdx.x * 256 + threadIdx.x;
    if (gid >= NPTS) return;
    int cell = classify_point(gid, Ki_all, db, extr);
    idxT[gid] = cell;
    if (cell >= 0) {
        int b = gid / (Nc * Dc * HWc);
        atomicAdd(&cnt[b * BEV_HW + cell], 1.0f);
    }
}

__global__ __launch_bounds__(256) void k_scatterF(const float* __restrict__ feat,
                                                  const float* __restrict__ depth,
                                                  const int* __restrict__ idxT,
                                                  float* __restrict__ out) {
    __shared__ float s_dw[HWc];
    __shared__ int   s_idx[HWc];
    int blk = blockIdx.x;
    int bn  = blk / Dc;
    int b   = bn / Nc;
    int tid = threadIdx.x;
    const float* dp = depth + (size_t)blk * HWc;
    const int*   ip = idxT  + (size_t)blk * HWc;
    for (int p = tid; p < HWc; p += 256) { s_dw[p] = dp[p]; s_idx[p] = ip[p]; }
    __syncthreads();
    const float* fb = feat + (size_t)bn * Cc * HWc;
    float*       ob = out  + (size_t)b  * Cc * BEV_HW;
    for (int c = 0; c < Cc; c++) {
        const float* f = fb + (size_t)c * HWc;
        float*       o = ob + (size_t)c * BEV_HW;
        for (int p = tid; p < HWc; p += 256) {
            int cell = s_idx[p];
            if (cell >= 0) atomicAdd(&o[cell], __fmul_rn(f[p], s_dw[p]));
        }
    }
}

__global__ __launch_bounds__(256) void k_normF(float* __restrict__ out,
                                               const float* __restrict__ cnt) {
    int i = blockIdx.x * 256 + threadIdx.x;
    const int total = Bc * Cc * BEV_HW / 4;
    if (i >= total) return;
    int q = i % (BEV_HW / 4);
    int b = i / (Cc * BEV_HW / 4);
    float4 v = ((float4*)out)[i];
    float4 cv = ((const float4*)cnt)[b * (BEV_HW / 4) + q];
    v.x = __fdiv_rn(v.x, __fadd_rn(cv.x, 1e-5f));
    v.y = __fdiv_rn(v.y, __fadd_rn(cv.y, 1e-5f));
    v.z = __fdiv_rn(v.z, __fadd_rn(cv.z, 1e-5f));
    v.w = __fdiv_rn(v.w, __fadd_rn(cv.w, 1e-5f));
    ((float4*)out)[i] = v;
}

// ===========================================================================
extern "C" void kernel_launch(void* const* d_in, const int* in_sizes, int n_in,
                              void* d_out, int out_size, void* d_ws, size_t ws_size,
                              hipStream_t stream) {
    const float* feat  = (const float*)d_in[0];
    const float* depth = (const float*)d_in[1];
    const float* intr  = (const float*)d_in[2];
    const float* extr  = (const float*)d_in[3];
    const int*   imh   = (const int*)d_in[4];
    const int*   imw   = (const int*)d_in[5];
    float* out = (float*)d_out;
    char*  ws  = (char*)d_ws;

    if (ws_size >= (size_t)WS_NEED) {
        int*   cntA = (int*)(ws + OFF_CNT);
        int*   offs = (int*)(ws + OFF_OFFS);
        int*   fill = (int*)(ws + OFF_FILL);
        int*   bsum = (int*)(ws + OFF_BSUM);
        int2*  e8   = (int2*)(ws + OFF_E8);
        float* ft   = (float*)(ws + OFF_FT);

        hipMemsetAsync(cntA, 0, (size_t)NSEG * sizeof(int), stream);
        k_count<<<NPTS / 256, 256, 0, stream>>>(intr, extr, imh, imw, feat, cntA, ft);
        k_scan1<<<NSEG / 512, 512, 0, stream>>>(cntA, offs, fill, bsum);
        k_scan2<<<1, 256, 0, stream>>>(bsum);
        k_fill<<<NPTS / 256, 256, 0, stream>>>(intr, extr, imh, imw, depth, fill, bsum, e8);
        k_gather<<<NTILE, 256, 0, stream>>>((const float2*)ft, e8, cntA, offs, bsum, out);
    } else {
        float* Ki   = (float*)(ws + OFF_KI);
        float* db   = (float*)(ws + OFF_DB);
        int*   idxT = (int*)(ws + OFF_FIDX);
        float* cnt  = (float*)(ws + OFF_FCNT);
        hipMemsetAsync(out, 0, (size_t)out_size * sizeof(float), stream);
        hipMemsetAsync(cnt, 0, (size_t)Bc * BEV_HW * sizeof(float), stream);
        k_setup<<<1, 64, 0, stream>>>(intr, extr, imh, imw, Ki, db);
        k_classifyF<<<(NPTS + 255) / 256, 256, 0, stream>>>(Ki, db, extr, idxT, cnt);
        k_scatterF<<<Bc * Nc * Dc, 256, 0, stream>>>(feat, depth, idxT, out);
        k_normF<<<(Bc * Cc * BEV_HW / 4 + 255) / 256, 256, 0, stream>>>(out, cnt);
    }
}